// Round 9
// baseline (368.754 us; speedup 1.0000x reference)
//
#include <hip/hip_runtime.h>
#include <stdint.h>

#define HEADS 8
#define DM 512
#define TT 12
#define WIN 3
#define NN 325
#define BB 4
#define HD 64
#define MROWS (BB*TT*NN)                  // 15600 rows for QKV gemm
#define NSLAB (BB*TT*HEADS)               // 384 head-slabs
#define NKT 11                            // 32-key tiles per slab (11*32=352)
static const size_t QKV_ELE = (size_t)MROWS * DM;           // 7,987,200 elems per tensor
static const size_t FRAG_SLAB = (size_t)NKT * 4 * 64 * 8;   // 22528 elems per slab frag tensor

typedef unsigned short u16;
typedef __attribute__((ext_vector_type(8))) short bf16x8;
typedef __attribute__((ext_vector_type(4))) float f32x4;

#define MFMA(a,b,c) __builtin_amdgcn_mfma_f32_16x16x32_bf16(a, b, c, 0, 0, 0)

static __device__ __forceinline__ float ex2(float x) {
  float r; asm("v_exp_f32 %0, %1" : "=v"(r) : "v"(x)); return r;
}

static __device__ __forceinline__ u16 f2bf(float f) {
  uint32_t u = __float_as_uint(f);
  u += 0x7fff + ((u >> 16) & 1);   // RNE
  return (u16)(u >> 16);
}
// pack two f32 -> one u32 of 2 bf16 (truncating), lo in low half
static __device__ __forceinline__ uint32_t pk2(float hi, float lo) {
  return __builtin_amdgcn_perm(__float_as_uint(hi), __float_as_uint(lo), 0x07060302);
}
static __device__ __forceinline__ float bf2f(u16 h) {
  return __uint_as_float((uint32_t)h << 16);
}

// ---------------- pack W (RNE) + bias concat ----------------
__global__ void pack_w(const float* __restrict__ Wq, const float* __restrict__ Wk,
                       const float* __restrict__ Wv, const float* __restrict__ bq,
                       const float* __restrict__ bk, const float* __restrict__ bv,
                       u16* __restrict__ Wb, float* __restrict__ biasc) {
  int i = blockIdx.x * blockDim.x + threadIdx.x;
  const int n4 = (3 * 512 * 512) / 4;   // 196608
  if (i < n4) {
    int j = i << 2;
    int which = j >> 18;                 // 512*512 = 2^18
    int off4 = i & ((512 * 512 / 4) - 1);
    const float* src = which == 0 ? Wq : (which == 1 ? Wk : Wv);
    float4 v = ((const float4*)src)[off4];
    uint32_t a0 = (uint32_t)f2bf(v.x) | ((uint32_t)f2bf(v.y) << 16);
    uint32_t a1 = (uint32_t)f2bf(v.z) | ((uint32_t)f2bf(v.w) << 16);
    ((uint2*)Wb)[i] = make_uint2(a0, a1);
  }
  if (i < 1536 / 4) {
    int j = i << 2;
    int which = j >> 9;
    int off4 = i & 127;
    const float* src = which == 0 ? bq : (which == 1 ? bk : bv);
    ((float4*)biasc)[i] = ((const float4*)src)[off4];
  }
}

// ---------------- fused QKV projection GEMM (row-major q,k,v out) ----------------
__global__ __launch_bounds__(256) void proj_gemm(
    const float* __restrict__ x,    // [M][512] f32
    const u16* __restrict__ W,      // [1536][512] bf16
    const float* __restrict__ bias, // [1536]
    u16* __restrict__ qkv)          // 3 x [B][T][H][N][64] bf16
{
  __shared__ u16 sA[128 * 32];
  __shared__ u16 sB[128 * 32];
  const int m0 = blockIdx.x * 128;
  const int n0 = blockIdx.y * 128;
  const int tid = threadIdx.x;
  const int lane = tid & 63;
  const int wid = tid >> 6;
  const int wr = wid >> 1, wc = wid & 1;

  f32x4 acc[4][4] = {};

  const int srow = tid >> 2;
  const int scol = (tid & 3) * 8;

  for (int k0 = 0; k0 < 512; k0 += 32) {
    __syncthreads();
#pragma unroll
    for (int i = 0; i < 2; ++i) {
      int row = i * 64 + srow;
      int gm = m0 + row; if (gm >= MROWS) gm = MROWS - 1;
      const float* xa = x + (size_t)gm * 512 + k0 + scol;
      float4 f0 = *(const float4*)xa;
      float4 f1 = *(const float4*)(xa + 4);
      uint4 u;
      u.x = pk2(f0.y, f0.x);
      u.y = pk2(f0.w, f0.z);
      u.z = pk2(f1.y, f1.x);
      u.w = pk2(f1.w, f1.z);
      *(uint4*)&sA[row * 32 + scol] = u;
      *(bf16x8*)&sB[row * 32 + scol] = *(const bf16x8*)&W[(size_t)(n0 + row) * 512 + k0 + scol];
    }
    __syncthreads();
    bf16x8 af[4], bfr[4];
#pragma unroll
    for (int mi = 0; mi < 4; ++mi)
      af[mi] = *(const bf16x8*)&sA[(wr * 64 + mi * 16 + (lane & 15)) * 32 + (lane >> 4) * 8];
#pragma unroll
    for (int ni = 0; ni < 4; ++ni)
      bfr[ni] = *(const bf16x8*)&sB[(wc * 64 + ni * 16 + (lane & 15)) * 32 + (lane >> 4) * 8];
#pragma unroll
    for (int mi = 0; mi < 4; ++mi)
#pragma unroll
      for (int ni = 0; ni < 4; ++ni)
        acc[mi][ni] = MFMA(af[mi], bfr[ni], acc[mi][ni]);
  }

  const int lr = (lane >> 4) * 4;
  const int lc = lane & 15;
#pragma unroll
  for (int mi = 0; mi < 4; ++mi) {
#pragma unroll
    for (int j = 0; j < 4; ++j) {
      int gm = m0 + wr * 64 + mi * 16 + lr + j;
      if (gm < MROWS) {
        int b = gm / (TT * NN);
        int rem = gm - b * (TT * NN);
        int t = rem / NN;
        int n = rem - t * NN;
#pragma unroll
        for (int ni = 0; ni < 4; ++ni) {
          int e = n0 + wc * 64 + ni * 16 + lc;
          float val = acc[mi][ni][j] + bias[e];
          int which = e >> 9;
          int h = (e >> 6) & 7;
          int d = e & 63;
          qkv[(size_t)which * QKV_ELE + ((((size_t)(b * TT + t) * HEADS + h) * NN + n) << 6) + d] = f2bf(val);
        }
      }
    }
  }
}

// ---------------- K/V row-major -> MFMA fragment layout (coalesced both sides) ----------------
// kf[slab][kt][f][lane][8]: K[kt*32 + rmap(qi) + (f>>1)*4][(f&1)*32 + g*8 + e], rmap=((qi>>2)<<3)|(qi&3)
// vf[slab][kt][dt][lane][8]: V[kt*32 + g*8 + e][dt*16 + qi]
// pad rows (>=325) written as zeros.
__global__ __launch_bounds__(256) void kv_pack(const u16* __restrict__ qkv,
                                               u16* __restrict__ kf, u16* __restrict__ vf) {
  int slab = blockIdx.x;
  const u16* K = qkv + QKV_ELE + ((size_t)slab * NN << 6);
  const u16* V = qkv + 2 * QKV_ELE + ((size_t)slab * NN << 6);
  u16* kout = kf + (size_t)slab * FRAG_SLAB;
  u16* vout = vf + (size_t)slab * FRAG_SLAB;
  int t = threadIdx.x;
  int f = t >> 6;           // 0..3
  int lane = t & 63;
  int qi = lane & 15, g = lane >> 4;
  int krow_l = ((qi >> 2) << 3) + (qi & 3) + ((f >> 1) << 2);
  int kd = ((f & 1) << 5) + g * 8;
  for (int kt = 0; kt < NKT; ++kt) {
    int row = kt * 32 + krow_l;
    bf16x8 kv = {};
    if (row < NN) kv = *(const bf16x8*)(K + ((size_t)row << 6) + kd);
    *(bf16x8*)(kout + ((size_t)kt * 4 + f) * 512 + lane * 8) = kv;
    union { u16 e[8]; bf16x8 v; } vv;
#pragma unroll
    for (int e = 0; e < 8; ++e) {
      int vrow = kt * 32 + g * 8 + e;
      vv.e[e] = (vrow < NN) ? V[((size_t)vrow << 6) + f * 16 + qi] : (u16)0;
    }
    *(bf16x8*)(vout + ((size_t)kt * 4 + f) * 512 + lane * 8) = vv.v;
  }
}

// ---------------- adj -> fragment layout f32 (coalesced writes) ----------------
// adjp[((slab*6+qt)*11+kt)*2048 + s*512 + lane*8 + e] = adj[slab][q0+s*16+qi][kt*32+g*8+e]
// cols >= 325 -> 0 (pad keys contribute exactly e^-8, corrected in attn epilogue)
__global__ __launch_bounds__(256) void adj_pack(const float* __restrict__ adj,
                                                float* __restrict__ adjp) {
  int blk = blockIdx.x;           // (slab*6 + qt)*11 + kt
  int kt = blk % 11;
  int rest = blk / 11;
  int qt = rest % 6;
  int slab = rest / 6;            // b*12 + ta
  const float* src = adj + (size_t)slab * NN * NN;
  float* dst = adjp + (size_t)blk * 2048;
  int t = threadIdx.x;
  int s = t >> 6, lane = t & 63;
  int qi = lane & 15, g = lane >> 4;
  int row = qt * 64 + s * 16 + qi; if (row > NN - 1) row = NN - 1;
  int c0 = kt * 32 + g * 8;
  const float* sp = src + (size_t)row * NN;
  float v[8];
#pragma unroll
  for (int e = 0; e < 8; ++e) {
    int c = c0 + e;
    v[e] = (c < NN) ? sp[c] : 0.0f;
  }
  float4 w0 = {v[0], v[1], v[2], v[3]};
  float4 w1 = {v[4], v[5], v[6], v[7]};
  *(float4*)(dst + t * 8) = w0;
  *(float4*)(dst + t * 8 + 4) = w1;
}

// ---------------- MFMA attention, v8: v7 + 3 blocks/CU residency ----------------
// Block = 4 waves = 4 heads of one (b,t,ti,qt); NO LDS, NO barriers. Per tile:
// 16 coalesced prefetch loads (adj 8, K 4, V 4) for kt+1, then compute kt.
// launch_bounds(256,3): VGPR cap 170 (usage 128) -> 3 blocks/CU, 3 waves/SIMD.
__global__ __launch_bounds__(256, 3) void attn(
    const u16* __restrict__ q,      // [B][T][H][N][64] bf16
    const u16* __restrict__ kf,     // K fragments
    const u16* __restrict__ vf,     // V fragments
    const float* __restrict__ adjp, // adj fragments
    u16* __restrict__ hcat)         // [B][36][N][512] bf16
{
  const int tid = threadIdx.x;
  const int wid = tid >> 6;
  const int lane = tid & 63;
  const int qi = lane & 15;
  const int g = lane >> 4;

  // XCD swizzle: nwg = 1728 = 8 * 216
  int ord = (blockIdx.x & 7) * 216 + (blockIdx.x >> 3);
  int slab = ord / 36;               // 0..47 = b*12 + ta
  int inner = ord - slab * 36;
  int b = slab / 12;
  int ta = slab - b * 12;            // t_adj
  int ti = inner / 12;
  int r2 = inner - ti * 12;
  int qt = r2 >> 1;
  int hg = r2 & 1;

  int tadd = ti == 0 ? 3 : (ti == 1 ? 2 : 1);           // t = ta + tadd (mod 12)
  int ckv  = ti == 0 ? 9 : (ti == 1 ? 7 : 6);           // t_kv = t + ckv (mod 12)
  float qsc = ti == 0 ? 0.125f : (ti == 1 ? 0.015625f : 0.001953125f);
  int t = ta + tadd; if (t >= 12) t -= 12;
  int t_kv = t + ckv; if (t_kv >= 12) t_kv -= 12;
  int h = hg * 4 + wid;
  int q0 = qt * 64;

  const u16* qbase = q + ((((size_t)(b * TT + t) * HEADS + h) * NN) << 6);
  int kvslab = (b * TT + t_kv) * HEADS + h;
  const u16* kfb = kf + (size_t)kvslab * FRAG_SLAB + lane * 8;
  const u16* vfb = vf + (size_t)kvslab * FRAG_SLAB + lane * 8;
  const float* apb = adjp + (size_t)(slab * 6 + qt) * (11 * 2048) + lane * 8;

  // Q fragments (B-operand)
  bf16x8 qf[4][2];
#pragma unroll
  for (int s = 0; s < 4; ++s) {
    int qr = q0 + s * 16 + qi; if (qr > NN - 1) qr = NN - 1;
    const u16* qp = qbase + ((size_t)qr << 6) + g * 8;
    qf[s][0] = *(const bf16x8*)qp;
    qf[s][1] = *(const bf16x8*)(qp + 32);
  }

  const f32x4 z4 = {0.f, 0.f, 0.f, 0.f};
  const float LG = 1.44269504f;
  const float C8 = -11.5415603f;     // -8*log2(e)

  f32x4 acc[4][4] = {};
  float lsum[4] = {0.f, 0.f, 0.f, 0.f};

  // tile-0 prefetch
  float4 fa[4], fb4[4];
  bf16x8 kc[4], vc[4];
#pragma unroll
  for (int s = 0; s < 4; ++s) {
    fa[s]  = *(const float4*)(apb + s * 512);
    fb4[s] = *(const float4*)(apb + s * 512 + 4);
  }
#pragma unroll
  for (int f = 0; f < 4; ++f) kc[f] = *(const bf16x8*)(kfb + f * 512);
#pragma unroll
  for (int f = 0; f < 4; ++f) vc[f] = *(const bf16x8*)(vfb + f * 512);

  for (int kt = 0; kt < 11; ++kt) {
    // ---- prefetch tile kt+1 (16 coalesced loads) ----
    float4 fan[4], fbn[4];
    bf16x8 kn[4], vn[4];
    if (kt < 10) {
      const float* ap = apb + (size_t)(kt + 1) * 2048;
#pragma unroll
      for (int s = 0; s < 4; ++s) {
        fan[s] = *(const float4*)(ap + s * 512);
        fbn[s] = *(const float4*)(ap + s * 512 + 4);
      }
      const u16* kp = kfb + (size_t)(kt + 1) * 2048;
      const u16* vp = vfb + (size_t)(kt + 1) * 2048;
#pragma unroll
      for (int f = 0; f < 4; ++f) kn[f] = *(const bf16x8*)(kp + f * 512);
#pragma unroll
      for (int f = 0; f < 4; ++f) vn[f] = *(const bf16x8*)(vp + f * 512);
    }

    // ---- compute tile kt ----
#pragma unroll
    for (int s = 0; s < 4; ++s) {
      f32x4 s0 = MFMA(kc[0], qf[s][0], z4);
      s0 = MFMA(kc[1], qf[s][1], s0);
      f32x4 s1 = MFMA(kc[2], qf[s][0], z4);
      s1 = MFMA(kc[3], qf[s][1], s1);
      float p[8];
      float av;
      av = fa[s].x;  p[0] = ex2(__builtin_fmaf(__builtin_fmaf(s0[0], av * qsc, av), LG, C8));
      av = fa[s].y;  p[1] = ex2(__builtin_fmaf(__builtin_fmaf(s0[1], av * qsc, av), LG, C8));
      av = fa[s].z;  p[2] = ex2(__builtin_fmaf(__builtin_fmaf(s0[2], av * qsc, av), LG, C8));
      av = fa[s].w;  p[3] = ex2(__builtin_fmaf(__builtin_fmaf(s0[3], av * qsc, av), LG, C8));
      av = fb4[s].x; p[4] = ex2(__builtin_fmaf(__builtin_fmaf(s1[0], av * qsc, av), LG, C8));
      av = fb4[s].y; p[5] = ex2(__builtin_fmaf(__builtin_fmaf(s1[1], av * qsc, av), LG, C8));
      av = fb4[s].z; p[6] = ex2(__builtin_fmaf(__builtin_fmaf(s1[2], av * qsc, av), LG, C8));
      av = fb4[s].w; p[7] = ex2(__builtin_fmaf(__builtin_fmaf(s1[3], av * qsc, av), LG, C8));
      lsum[s] += ((p[0] + p[1]) + (p[2] + p[3])) + ((p[4] + p[5]) + (p[6] + p[7]));
      union { uint32_t u[4]; bf16x8 v; } pu;
      pu.u[0] = pk2(p[1], p[0]);
      pu.u[1] = pk2(p[3], p[2]);
      pu.u[2] = pk2(p[5], p[4]);
      pu.u[3] = pk2(p[7], p[6]);
      acc[s][0] = MFMA(pu.v, vc[0], acc[s][0]);
      acc[s][1] = MFMA(pu.v, vc[1], acc[s][1]);
      acc[s][2] = MFMA(pu.v, vc[2], acc[s][2]);
      acc[s][3] = MFMA(pu.v, vc[3], acc[s][3]);
    }
#pragma unroll
    for (int s = 0; s < 4; ++s) { fa[s] = fan[s]; fb4[s] = fbn[s]; }
#pragma unroll
    for (int f = 0; f < 4; ++f) { kc[f] = kn[f]; vc[f] = vn[f]; }
  }

  // ---- epilogue: exact pad correction, normalize, store ----
  const float padcorr = 27.0f * ex2(C8);   // 27 pad keys, each contributes exactly 2^C8
  size_t hb = ((size_t)(b * 36 + ti * TT + t) * NN) << 9;
#pragma unroll
  for (int s = 0; s < 4; ++s) {
    float v = lsum[s];
    v += __shfl_xor(v, 16);
    v += __shfl_xor(v, 32);
    v -= padcorr;
    float linv = 1.0f / v;
#pragma unroll
    for (int j = 0; j < 4; ++j) {
      float li = __shfl(linv, g * 4 + j);
      int qrow = q0 + s * 16 + 4 * g + j;
      if (qrow < NN) {
        u16* op = hcat + hb + ((size_t)qrow << 9) + h * 64 + qi;
#pragma unroll
        for (int dt = 0; dt < 4; ++dt)
          op[dt * 16] = f2bf(acc[s][dt][j] * li);
      }
    }
  }
}

// ---------------- temporal mix + residual + LayerNorm ----------------
__global__ __launch_bounds__(256) void mix_ln(
    const u16* __restrict__ hcat,
    const float* __restrict__ Wd,   // [12][36]
    const float* __restrict__ bd,   // [12]
    const float* __restrict__ x,
    const float* __restrict__ gamma,
    const float* __restrict__ beta,
    float* __restrict__ out)
{
  __shared__ float sH[36 * 512];
  __shared__ float sWd[12 * 36];
  __shared__ float sred[8];
  int bn = blockIdx.x;
  int b = bn / NN, n = bn - b * NN;
  int tid = threadIdx.x;
  int lane = tid & 63, wid = tid >> 6;

  for (int i = tid; i < 12 * 36; i += 256) sWd[i] = Wd[i];
  for (int i = tid; i < 36 * 512; i += 256) {
    int w = i >> 9, d = i & 511;
    sH[i] = bf2f(hcat[(((size_t)(b * 36 + w) * NN + n) << 9) + d]);
  }
  __syncthreads();

  for (int t = 0; t < TT; ++t) {
    float a0 = 0.f, a1 = 0.f;
#pragma unroll
    for (int w = 0; w < 36; ++w) {
      float wv = sWd[t * 36 + w];
      a0 += sH[(w << 9) + tid] * wv;
      a1 += sH[(w << 9) + 256 + tid] * wv;
    }
    size_t xoff = ((size_t)(b * TT + t) * NN + n) << 9;
    float bdt = bd[t];
    float y0 = a0 + bdt + x[xoff + tid];
    float y1 = a1 + bdt + x[xoff + 256 + tid];
    float s = y0 + y1, ss = y0 * y0 + y1 * y1;
#pragma unroll
    for (int off = 32; off > 0; off >>= 1) {
      s += __shfl_down(s, off);
      ss += __shfl_down(ss, off);
    }
    if (lane == 0) { sred[wid * 2] = s; sred[wid * 2 + 1] = ss; }
    __syncthreads();
    float stot = sred[0] + sred[2] + sred[4] + sred[6];
    float sstot = sred[1] + sred[3] + sred[5] + sred[7];
    float mu = stot * (1.0f / 512.0f);
    float var = sstot * (1.0f / 512.0f) - mu * mu;
    float rstd = rsqrtf(var + 1e-5f);
    out[xoff + tid] = (y0 - mu) * rstd * gamma[tid] + beta[tid];
    out[xoff + 256 + tid] = (y1 - mu) * rstd * gamma[tid + 256] + beta[tid + 256];
    __syncthreads();
  }
}

extern "C" void kernel_launch(void* const* d_in, const int* in_sizes, int n_in,
                              void* d_out, int out_size, void* d_ws, size_t ws_size,
                              hipStream_t stream) {
  const float* x     = (const float*)d_in[0];
  const float* adj   = (const float*)d_in[1];
  // d_in[2] = s_adj: unused by the reference
  const float* Wq    = (const float*)d_in[3];
  const float* bq    = (const float*)d_in[4];
  const float* Wk    = (const float*)d_in[5];
  const float* bk    = (const float*)d_in[6];
  const float* Wv    = (const float*)d_in[7];
  const float* bv    = (const float*)d_in[8];
  const float* Wd    = (const float*)d_in[9];
  const float* bd    = (const float*)d_in[10];
  const float* gamma = (const float*)d_in[11];
  const float* beta  = (const float*)d_in[12];
  float* out = (float*)d_out;

  char* ws = (char*)d_ws;
  size_t off = 0;
  auto alloc = [&](size_t bytes) {
    void* p = ws + off;
    off += (bytes + 255) & ~(size_t)255;
    return p;
  };
  u16* Wb     = (u16*)alloc(1536 * 512 * 2);               // [Wq;Wk;Wv] bf16
  float* bias = (float*)alloc(1536 * 4);                   // [bq;bk;bv]
  u16* qkv    = (u16*)alloc(3 * QKV_ELE * 2);              // q,k,v bf16 row-major
  u16* hcat   = (u16*)alloc(3 * QKV_ELE * 2);              // (B,36,N,512) bf16
  u16* kfb    = (u16*)alloc((size_t)NSLAB * FRAG_SLAB * 2);   // K fragments
  u16* vfb    = (u16*)alloc((size_t)NSLAB * FRAG_SLAB * 2);   // V fragments
  float* adjp = (float*)alloc((size_t)48 * 6 * 11 * 2048 * 4); // adj fragments

  adj_pack<<<dim3(48 * 6 * 11), dim3(256), 0, stream>>>(adj, adjp);
  pack_w<<<dim3(768), dim3(256), 0, stream>>>(Wq, Wk, Wv, bq, bk, bv, Wb, bias);
  proj_gemm<<<dim3((MROWS + 127) / 128, 1536 / 128), dim3(256), 0, stream>>>(x, Wb, bias, qkv);
  kv_pack<<<dim3(NSLAB), dim3(256), 0, stream>>>(qkv, kfb, vfb);
  attn<<<dim3(BB * TT * WIN * 6 * 2), dim3(256), 0, stream>>>(qkv, kfb, vfb, adjp, hcat);
  mix_ln<<<dim3(BB * NN), dim3(256), 0, stream>>>(hcat, Wd, bd, x, gamma, beta, out);
}

// Round 10
// 233.086 us; speedup vs baseline: 1.5820x; 1.5820x over previous
//
#include <hip/hip_runtime.h>
#include <stdint.h>

#define HEADS 8
#define DM 512
#define TT 12
#define WIN 3
#define NN 325
#define BB 4
#define HD 64
#define MROWS (BB*TT*NN)                  // 15600 rows for QKV gemm
#define NSLAB (BB*TT*HEADS)               // 384 head-slabs
#define NKT 11                            // 32-key tiles per slab (11*32=352)
static const size_t QKV_ELE = (size_t)MROWS * DM;           // 7,987,200 elems per tensor
static const size_t FRAG_SLAB = (size_t)NKT * 4 * 64 * 8;   // 22528 elems per slab frag tensor

typedef unsigned short u16;
typedef __attribute__((ext_vector_type(8))) short bf16x8;
typedef __attribute__((ext_vector_type(4))) float f32x4;

#define MFMA(a,b,c) __builtin_amdgcn_mfma_f32_16x16x32_bf16(a, b, c, 0, 0, 0)

static __device__ __forceinline__ float ex2(float x) {
  float r; asm("v_exp_f32 %0, %1" : "=v"(r) : "v"(x)); return r;
}

static __device__ __forceinline__ u16 f2bf(float f) {
  uint32_t u = __float_as_uint(f);
  u += 0x7fff + ((u >> 16) & 1);   // RNE
  return (u16)(u >> 16);
}
// pack two f32 -> one u32 of 2 bf16 (truncating), lo in low half
static __device__ __forceinline__ uint32_t pk2(float hi, float lo) {
  return __builtin_amdgcn_perm(__float_as_uint(hi), __float_as_uint(lo), 0x07060302);
}
static __device__ __forceinline__ float bf2f(u16 h) {
  return __uint_as_float((uint32_t)h << 16);
}

// global -> LDS async DMA, 16B per lane (lds dest is wave-uniform base + lane*16)
typedef const __attribute__((address_space(1))) unsigned int* gas1;
typedef __attribute__((address_space(3))) unsigned int* las3;
static __device__ __forceinline__ void gll16(const void* g, void* l) {
  __builtin_amdgcn_global_load_lds((gas1)g, (las3)l, 16, 0, 0);
}

// ---------------- pack W (RNE) + bias concat ----------------
__global__ void pack_w(const float* __restrict__ Wq, const float* __restrict__ Wk,
                       const float* __restrict__ Wv, const float* __restrict__ bq,
                       const float* __restrict__ bk, const float* __restrict__ bv,
                       u16* __restrict__ Wb, float* __restrict__ biasc) {
  int i = blockIdx.x * blockDim.x + threadIdx.x;
  const int n4 = (3 * 512 * 512) / 4;   // 196608
  if (i < n4) {
    int j = i << 2;
    int which = j >> 18;                 // 512*512 = 2^18
    int off4 = i & ((512 * 512 / 4) - 1);
    const float* src = which == 0 ? Wq : (which == 1 ? Wk : Wv);
    float4 v = ((const float4*)src)[off4];
    uint32_t a0 = (uint32_t)f2bf(v.x) | ((uint32_t)f2bf(v.y) << 16);
    uint32_t a1 = (uint32_t)f2bf(v.z) | ((uint32_t)f2bf(v.w) << 16);
    ((uint2*)Wb)[i] = make_uint2(a0, a1);
  }
  if (i < 1536 / 4) {
    int j = i << 2;
    int which = j >> 9;
    int off4 = i & 127;
    const float* src = which == 0 ? bq : (which == 1 ? bk : bv);
    ((float4*)biasc)[i] = ((const float4*)src)[off4];
  }
}

// ---------------- fused QKV projection GEMM (row-major q,k,v out) ----------------
__global__ __launch_bounds__(256) void proj_gemm(
    const float* __restrict__ x,    // [M][512] f32
    const u16* __restrict__ W,      // [1536][512] bf16
    const float* __restrict__ bias, // [1536]
    u16* __restrict__ qkv)          // 3 x [B][T][H][N][64] bf16
{
  __shared__ u16 sA[128 * 32];
  __shared__ u16 sB[128 * 32];
  const int m0 = blockIdx.x * 128;
  const int n0 = blockIdx.y * 128;
  const int tid = threadIdx.x;
  const int lane = tid & 63;
  const int wid = tid >> 6;
  const int wr = wid >> 1, wc = wid & 1;

  f32x4 acc[4][4] = {};

  const int srow = tid >> 2;
  const int scol = (tid & 3) * 8;

  for (int k0 = 0; k0 < 512; k0 += 32) {
    __syncthreads();
#pragma unroll
    for (int i = 0; i < 2; ++i) {
      int row = i * 64 + srow;
      int gm = m0 + row; if (gm >= MROWS) gm = MROWS - 1;
      const float* xa = x + (size_t)gm * 512 + k0 + scol;
      float4 f0 = *(const float4*)xa;
      float4 f1 = *(const float4*)(xa + 4);
      uint4 u;
      u.x = pk2(f0.y, f0.x);
      u.y = pk2(f0.w, f0.z);
      u.z = pk2(f1.y, f1.x);
      u.w = pk2(f1.w, f1.z);
      *(uint4*)&sA[row * 32 + scol] = u;
      *(bf16x8*)&sB[row * 32 + scol] = *(const bf16x8*)&W[(size_t)(n0 + row) * 512 + k0 + scol];
    }
    __syncthreads();
    bf16x8 af[4], bfr[4];
#pragma unroll
    for (int mi = 0; mi < 4; ++mi)
      af[mi] = *(const bf16x8*)&sA[(wr * 64 + mi * 16 + (lane & 15)) * 32 + (lane >> 4) * 8];
#pragma unroll
    for (int ni = 0; ni < 4; ++ni)
      bfr[ni] = *(const bf16x8*)&sB[(wc * 64 + ni * 16 + (lane & 15)) * 32 + (lane >> 4) * 8];
#pragma unroll
    for (int mi = 0; mi < 4; ++mi)
#pragma unroll
      for (int ni = 0; ni < 4; ++ni)
        acc[mi][ni] = MFMA(af[mi], bfr[ni], acc[mi][ni]);
  }

  const int lr = (lane >> 4) * 4;
  const int lc = lane & 15;
#pragma unroll
  for (int mi = 0; mi < 4; ++mi) {
#pragma unroll
    for (int j = 0; j < 4; ++j) {
      int gm = m0 + wr * 64 + mi * 16 + lr + j;
      if (gm < MROWS) {
        int b = gm / (TT * NN);
        int rem = gm - b * (TT * NN);
        int t = rem / NN;
        int n = rem - t * NN;
#pragma unroll
        for (int ni = 0; ni < 4; ++ni) {
          int e = n0 + wc * 64 + ni * 16 + lc;
          float val = acc[mi][ni][j] + bias[e];
          int which = e >> 9;
          int h = (e >> 6) & 7;
          int d = e & 63;
          qkv[(size_t)which * QKV_ELE + ((((size_t)(b * TT + t) * HEADS + h) * NN + n) << 6) + d] = f2bf(val);
        }
      }
    }
  }
}

// ---------------- K/V row-major -> MFMA fragment layout (coalesced both sides) ----------------
// kf[slab][kt][f][lane][8]: K[kt*32 + rmap(qi) + (f>>1)*4][(f&1)*32 + g*8 + e], rmap=((qi>>2)<<3)|(qi&3)
// vf[slab][kt][dt][lane][8]: V[kt*32 + g*8 + e][dt*16 + qi]
// pad rows (>=325) written as zeros.
__global__ __launch_bounds__(256) void kv_pack(const u16* __restrict__ qkv,
                                               u16* __restrict__ kf, u16* __restrict__ vf) {
  int slab = blockIdx.x;
  const u16* K = qkv + QKV_ELE + ((size_t)slab * NN << 6);
  const u16* V = qkv + 2 * QKV_ELE + ((size_t)slab * NN << 6);
  u16* kout = kf + (size_t)slab * FRAG_SLAB;
  u16* vout = vf + (size_t)slab * FRAG_SLAB;
  int t = threadIdx.x;
  int f = t >> 6;           // 0..3
  int lane = t & 63;
  int qi = lane & 15, g = lane >> 4;
  int krow_l = ((qi >> 2) << 3) + (qi & 3) + ((f >> 1) << 2);
  int kd = ((f & 1) << 5) + g * 8;
  for (int kt = 0; kt < NKT; ++kt) {
    int row = kt * 32 + krow_l;
    bf16x8 kv = {};
    if (row < NN) kv = *(const bf16x8*)(K + ((size_t)row << 6) + kd);
    *(bf16x8*)(kout + ((size_t)kt * 4 + f) * 512 + lane * 8) = kv;
    union { u16 e[8]; bf16x8 v; } vv;
#pragma unroll
    for (int e = 0; e < 8; ++e) {
      int vrow = kt * 32 + g * 8 + e;
      vv.e[e] = (vrow < NN) ? V[((size_t)vrow << 6) + f * 16 + qi] : (u16)0;
    }
    *(bf16x8*)(vout + ((size_t)kt * 4 + f) * 512 + lane * 8) = vv.v;
  }
}

// ---------------- adj -> fragment layout f32 (coalesced writes) ----------------
// adjp[((slab*6+qt)*11+kt)*2048 + s*512 + lane*8 + e] = adj[slab][q0+s*16+qi][kt*32+g*8+e]
// cols >= 325 -> 0 (pad keys contribute exactly e^-8, corrected in attn epilogue)
__global__ __launch_bounds__(256) void adj_pack(const float* __restrict__ adj,
                                                float* __restrict__ adjp) {
  int blk = blockIdx.x;           // (slab*6 + qt)*11 + kt
  int kt = blk % 11;
  int rest = blk / 11;
  int qt = rest % 6;
  int slab = rest / 6;            // b*12 + ta
  const float* src = adj + (size_t)slab * NN * NN;
  float* dst = adjp + (size_t)blk * 2048;
  int t = threadIdx.x;
  int s = t >> 6, lane = t & 63;
  int qi = lane & 15, g = lane >> 4;
  int row = qt * 64 + s * 16 + qi; if (row > NN - 1) row = NN - 1;
  int c0 = kt * 32 + g * 8;
  const float* sp = src + (size_t)row * NN;
  float v[8];
#pragma unroll
  for (int e = 0; e < 8; ++e) {
    int c = c0 + e;
    v[e] = (c < NN) ? sp[c] : 0.0f;
  }
  float4 w0 = {v[0], v[1], v[2], v[3]};
  float4 w1 = {v[4], v[5], v[6], v[7]};
  *(float4*)(dst + t * 8) = w0;
  *(float4*)(dst + t * 8 + 4) = w1;
}

// ---------------- MFMA attention, v9: K/V via global_load_lds DMA, barrier-free ----------------
// Block = 4 waves = 4 heads of one (b,t,ti,qt). Each wave stages ITS OWN K/V tile
// into its own LDS slice via global_load_lds (no VGPR cost, no barriers - a wave
// waits only its own vmcnt; in-order issue makes double-buffer reuse safe).
// adj stays 1-deep register prefetch. Per iteration exactly 16 VMEM ops are issued
// (8 gll + 8 adj loads), so s_waitcnt vmcnt(16) at the top of compute retires
// everything issued in PREVIOUS iterations (the gll's + adj this tile needs) while
// leaving the current iteration's 16 in flight. Last tile drains vmcnt(0).
__global__ __launch_bounds__(256, 2) void attn(
    const u16* __restrict__ q,      // [B][T][H][N][64] bf16
    const u16* __restrict__ kf,     // K fragments
    const u16* __restrict__ vf,     // V fragments
    const float* __restrict__ adjp, // adj fragments
    u16* __restrict__ hcat)         // [B][36][N][512] bf16
{
  // [wave][buf][K/V][frag][512 u16] = 64 KB
  __shared__ u16 kvlds[4][2][2][4][512];

  const int tid = threadIdx.x;
  const int wid = tid >> 6;
  const int lane = tid & 63;
  const int qi = lane & 15;
  const int g = lane >> 4;

  // XCD swizzle: nwg = 1728 = 8 * 216
  int ord = (blockIdx.x & 7) * 216 + (blockIdx.x >> 3);
  int slab = ord / 36;               // 0..47 = b*12 + ta
  int inner = ord - slab * 36;
  int b = slab / 12;
  int ta = slab - b * 12;            // t_adj
  int ti = inner / 12;
  int r2 = inner - ti * 12;
  int qt = r2 >> 1;
  int hg = r2 & 1;

  int tadd = ti == 0 ? 3 : (ti == 1 ? 2 : 1);           // t = ta + tadd (mod 12)
  int ckv  = ti == 0 ? 9 : (ti == 1 ? 7 : 6);           // t_kv = t + ckv (mod 12)
  float qsc = ti == 0 ? 0.125f : (ti == 1 ? 0.015625f : 0.001953125f);
  int t = ta + tadd; if (t >= 12) t -= 12;
  int t_kv = t + ckv; if (t_kv >= 12) t_kv -= 12;
  int h = hg * 4 + wid;
  int q0 = qt * 64;

  const u16* qbase = q + ((((size_t)(b * TT + t) * HEADS + h) * NN) << 6);
  int kvslab = (b * TT + t_kv) * HEADS + h;
  const u16* kfb = kf + (size_t)kvslab * FRAG_SLAB + lane * 8;   // per-lane global src
  const u16* vfb = vf + (size_t)kvslab * FRAG_SLAB + lane * 8;
  const float* apb = adjp + (size_t)(slab * 6 + qt) * (11 * 2048) + lane * 8;

  // Q fragments (B-operand)
  bf16x8 qf[4][2];
#pragma unroll
  for (int s = 0; s < 4; ++s) {
    int qr = q0 + s * 16 + qi; if (qr > NN - 1) qr = NN - 1;
    const u16* qp = qbase + ((size_t)qr << 6) + g * 8;
    qf[s][0] = *(const bf16x8*)qp;
    qf[s][1] = *(const bf16x8*)(qp + 32);
  }

  const f32x4 z4 = {0.f, 0.f, 0.f, 0.f};
  const float LG = 1.44269504f;
  const float C8 = -11.5415603f;     // -8*log2(e)

  f32x4 acc[4][4] = {};
  float lsum[4] = {0.f, 0.f, 0.f, 0.f};

  // ---- prologue: stage tile 0 (gll into buf0) + adj tile-0 register prefetch ----
#pragma unroll
  for (int f = 0; f < 4; ++f) {
    gll16(kfb + (size_t)f * 512, &kvlds[wid][0][0][f][0]);
    gll16(vfb + (size_t)f * 512, &kvlds[wid][0][1][f][0]);
  }
  float4 fa[4], fb4[4];
#pragma unroll
  for (int s = 0; s < 4; ++s) {
    fa[s]  = *(const float4*)(apb + s * 512);
    fb4[s] = *(const float4*)(apb + s * 512 + 4);
  }

  for (int kt = 0; kt < 11; ++kt) {
    int cur = kt & 1;
    // ---- issue tile kt+1: 8 gll + 8 adj register loads ----
    float4 fan[4], fbn[4];
    if (kt < 10) {
      const u16* kp = kfb + (size_t)(kt + 1) * 2048;
      const u16* vp = vfb + (size_t)(kt + 1) * 2048;
#pragma unroll
      for (int f = 0; f < 4; ++f) {
        gll16(kp + (size_t)f * 512, &kvlds[wid][cur ^ 1][0][f][0]);
        gll16(vp + (size_t)f * 512, &kvlds[wid][cur ^ 1][1][f][0]);
      }
      const float* ap = apb + (size_t)(kt + 1) * 2048;
#pragma unroll
      for (int s = 0; s < 4; ++s) {
        fan[s] = *(const float4*)(ap + s * 512);
        fbn[s] = *(const float4*)(ap + s * 512 + 4);
      }
      asm volatile("s_waitcnt vmcnt(16)" ::: "memory");
    } else {
      asm volatile("s_waitcnt vmcnt(0)" ::: "memory");
    }

    // ---- read this tile's K/V frags from LDS (lane-linear, conflict-free) ----
    bf16x8 kc[4], vc[4];
#pragma unroll
    for (int f = 0; f < 4; ++f) {
      kc[f] = *(const bf16x8*)&kvlds[wid][cur][0][f][lane * 8];
      vc[f] = *(const bf16x8*)&kvlds[wid][cur][1][f][lane * 8];
    }

    // ---- compute tile kt ----
#pragma unroll
    for (int s = 0; s < 4; ++s) {
      f32x4 s0 = MFMA(kc[0], qf[s][0], z4);
      s0 = MFMA(kc[1], qf[s][1], s0);
      f32x4 s1 = MFMA(kc[2], qf[s][0], z4);
      s1 = MFMA(kc[3], qf[s][1], s1);
      float p[8];
      float av;
      av = fa[s].x;  p[0] = ex2(__builtin_fmaf(__builtin_fmaf(s0[0], av * qsc, av), LG, C8));
      av = fa[s].y;  p[1] = ex2(__builtin_fmaf(__builtin_fmaf(s0[1], av * qsc, av), LG, C8));
      av = fa[s].z;  p[2] = ex2(__builtin_fmaf(__builtin_fmaf(s0[2], av * qsc, av), LG, C8));
      av = fa[s].w;  p[3] = ex2(__builtin_fmaf(__builtin_fmaf(s0[3], av * qsc, av), LG, C8));
      av = fb4[s].x; p[4] = ex2(__builtin_fmaf(__builtin_fmaf(s1[0], av * qsc, av), LG, C8));
      av = fb4[s].y; p[5] = ex2(__builtin_fmaf(__builtin_fmaf(s1[1], av * qsc, av), LG, C8));
      av = fb4[s].z; p[6] = ex2(__builtin_fmaf(__builtin_fmaf(s1[2], av * qsc, av), LG, C8));
      av = fb4[s].w; p[7] = ex2(__builtin_fmaf(__builtin_fmaf(s1[3], av * qsc, av), LG, C8));
      lsum[s] += ((p[0] + p[1]) + (p[2] + p[3])) + ((p[4] + p[5]) + (p[6] + p[7]));
      union { uint32_t u[4]; bf16x8 v; } pu;
      pu.u[0] = pk2(p[1], p[0]);
      pu.u[1] = pk2(p[3], p[2]);
      pu.u[2] = pk2(p[5], p[4]);
      pu.u[3] = pk2(p[7], p[6]);
      acc[s][0] = MFMA(pu.v, vc[0], acc[s][0]);
      acc[s][1] = MFMA(pu.v, vc[1], acc[s][1]);
      acc[s][2] = MFMA(pu.v, vc[2], acc[s][2]);
      acc[s][3] = MFMA(pu.v, vc[3], acc[s][3]);
    }
#pragma unroll
    for (int s = 0; s < 4; ++s) { fa[s] = fan[s]; fb4[s] = fbn[s]; }
  }

  // ---- epilogue: exact pad correction, normalize, store ----
  const float padcorr = 27.0f * ex2(C8);   // 27 pad keys, each contributes exactly 2^C8
  size_t hb = ((size_t)(b * 36 + ti * TT + t) * NN) << 9;
#pragma unroll
  for (int s = 0; s < 4; ++s) {
    float v = lsum[s];
    v += __shfl_xor(v, 16);
    v += __shfl_xor(v, 32);
    v -= padcorr;
    float linv = 1.0f / v;
#pragma unroll
    for (int j = 0; j < 4; ++j) {
      float li = __shfl(linv, g * 4 + j);
      int qrow = q0 + s * 16 + 4 * g + j;
      if (qrow < NN) {
        u16* op = hcat + hb + ((size_t)qrow << 9) + h * 64 + qi;
#pragma unroll
        for (int dt = 0; dt < 4; ++dt)
          op[dt * 16] = f2bf(acc[s][dt][j] * li);
      }
    }
  }
}

// ---------------- temporal mix + residual + LayerNorm ----------------
__global__ __launch_bounds__(256) void mix_ln(
    const u16* __restrict__ hcat,
    const float* __restrict__ Wd,   // [12][36]
    const float* __restrict__ bd,   // [12]
    const float* __restrict__ x,
    const float* __restrict__ gamma,
    const float* __restrict__ beta,
    float* __restrict__ out)
{
  __shared__ float sH[36 * 512];
  __shared__ float sWd[12 * 36];
  __shared__ float sred[8];
  int bn = blockIdx.x;
  int b = bn / NN, n = bn - b * NN;
  int tid = threadIdx.x;
  int lane = tid & 63, wid = tid >> 6;

  for (int i = tid; i < 12 * 36; i += 256) sWd[i] = Wd[i];
  for (int i = tid; i < 36 * 512; i += 256) {
    int w = i >> 9, d = i & 511;
    sH[i] = bf2f(hcat[(((size_t)(b * 36 + w) * NN + n) << 9) + d]);
  }
  __syncthreads();

  for (int t = 0; t < TT; ++t) {
    float a0 = 0.f, a1 = 0.f;
#pragma unroll
    for (int w = 0; w < 36; ++w) {
      float wv = sWd[t * 36 + w];
      a0 += sH[(w << 9) + tid] * wv;
      a1 += sH[(w << 9) + 256 + tid] * wv;
    }
    size_t xoff = ((size_t)(b * TT + t) * NN + n) << 9;
    float bdt = bd[t];
    float y0 = a0 + bdt + x[xoff + tid];
    float y1 = a1 + bdt + x[xoff + 256 + tid];
    float s = y0 + y1, ss = y0 * y0 + y1 * y1;
#pragma unroll
    for (int off = 32; off > 0; off >>= 1) {
      s += __shfl_down(s, off);
      ss += __shfl_down(ss, off);
    }
    if (lane == 0) { sred[wid * 2] = s; sred[wid * 2 + 1] = ss; }
    __syncthreads();
    float stot = sred[0] + sred[2] + sred[4] + sred[6];
    float sstot = sred[1] + sred[3] + sred[5] + sred[7];
    float mu = stot * (1.0f / 512.0f);
    float var = sstot * (1.0f / 512.0f) - mu * mu;
    float rstd = rsqrtf(var + 1e-5f);
    out[xoff + tid] = (y0 - mu) * rstd * gamma[tid] + beta[tid];
    out[xoff + 256 + tid] = (y1 - mu) * rstd * gamma[tid + 256] + beta[tid + 256];
    __syncthreads();
  }
}

extern "C" void kernel_launch(void* const* d_in, const int* in_sizes, int n_in,
                              void* d_out, int out_size, void* d_ws, size_t ws_size,
                              hipStream_t stream) {
  const float* x     = (const float*)d_in[0];
  const float* adj   = (const float*)d_in[1];
  // d_in[2] = s_adj: unused by the reference
  const float* Wq    = (const float*)d_in[3];
  const float* bq    = (const float*)d_in[4];
  const float* Wk    = (const float*)d_in[5];
  const float* bk    = (const float*)d_in[6];
  const float* Wv    = (const float*)d_in[7];
  const float* bv    = (const float*)d_in[8];
  const float* Wd    = (const float*)d_in[9];
  const float* bd    = (const float*)d_in[10];
  const float* gamma = (const float*)d_in[11];
  const float* beta  = (const float*)d_in[12];
  float* out = (float*)d_out;

  char* ws = (char*)d_ws;
  size_t off = 0;
  auto alloc = [&](size_t bytes) {
    void* p = ws + off;
    off += (bytes + 255) & ~(size_t)255;
    return p;
  };
  u16* Wb     = (u16*)alloc(1536 * 512 * 2);               // [Wq;Wk;Wv] bf16
  float* bias = (float*)alloc(1536 * 4);                   // [bq;bk;bv]
  u16* qkv    = (u16*)alloc(3 * QKV_ELE * 2);              // q,k,v bf16 row-major
  u16* hcat   = (u16*)alloc(3 * QKV_ELE * 2);              // (B,36,N,512) bf16
  u16* kfb    = (u16*)alloc((size_t)NSLAB * FRAG_SLAB * 2);   // K fragments
  u16* vfb    = (u16*)alloc((size_t)NSLAB * FRAG_SLAB * 2);   // V fragments
  float* adjp = (float*)alloc((size_t)48 * 6 * 11 * 2048 * 4); // adj fragments

  adj_pack<<<dim3(48 * 6 * 11), dim3(256), 0, stream>>>(adj, adjp);
  pack_w<<<dim3(768), dim3(256), 0, stream>>>(Wq, Wk, Wv, bq, bk, bv, Wb, bias);
  proj_gemm<<<dim3((MROWS + 127) / 128, 1536 / 128), dim3(256), 0, stream>>>(x, Wb, bias, qkv);
  kv_pack<<<dim3(NSLAB), dim3(256), 0, stream>>>(qkv, kfb, vfb);
  attn<<<dim3(BB * TT * WIN * 6 * 2), dim3(256), 0, stream>>>(qkv, kfb, vfb, adjp, hcat);
  mix_ln<<<dim3(BB * NN), dim3(256), 0, stream>>>(hcat, Wd, bd, x, gamma, beta, out);
}